// Round 13
// baseline (230.694 us; speedup 1.0000x reference)
//
#include <hip/hip_runtime.h>
#include <hip/hip_bf16.h>

typedef __attribute__((ext_vector_type(8))) __bf16 bf16x8;
typedef __attribute__((ext_vector_type(4))) __bf16 bf16x4;
typedef __attribute__((ext_vector_type(4))) float f32x4;

constexpr int M = 16384;
constexpr int K = 512;
constexpr int BK = 32;
constexpr int NT = 16;       // K / BK

__device__ __forceinline__ void async_copy16(const void* gsrc, void* ldst) {
  __builtin_amdgcn_global_load_lds(
      (const __attribute__((address_space(1))) unsigned int*)(gsrc),
      (__attribute__((address_space(3))) unsigned int*)(ldst),
      16, 0, 0);
}

__device__ __forceinline__ float frcp(float x) { return __builtin_amdgcn_rcpf(x); }
__device__ __forceinline__ float ftanh(float x) {
  return 1.0f - 2.0f * frcp(1.0f + __expf(2.0f * x));
}
__device__ __forceinline__ float fsigm(float x) { return frcp(1.0f + __expf(-x)); }

// Epilogue scratch swizzle (R4-proven): row stride 128 els (256B, bank-
// aligned); per-row XOR on the 8-el chunk gives the 4 kc row-groups distinct
// shifts -> stores 2-way max (free), reads cover each row once.
__device__ __forceinline__ int kswz(int row) {
  return ((row & 3) << 3) ^ ((row & 12) << 2);
}

// ---------------------------------------------------------------------------
// R13 = R11/R12 (best known 218.9us) with staging cut to TWO buffers ->
// LDS 32KB -> 5 blocks/CU (20 waves vs 12): the TLP axis, the only one not
// yet isolated. R12 POST-MORTEM: full unroll null (VALUBusy unchanged 38%)
// -> address-VALU theory wrong; counters still show the latency-bound
// signature (both pipes <25%, Occupancy 24%) = exposed staging drain. More
// resident blocks is the remaining mechanism that can fill it.
// Sync: R0/R4-proven 2-phase dbuf ordered by __syncthreads() (compiler
// emits the vmcnt/lgkm drain before s_barrier - zero race risk; counted
// vmcnt is inapplicable at lead-1 since the newest stage must land).
// Kept byte-identical: XCD chunk swizzle (R9), kswz epilogue (R4), nt
// stream-once hints (R11), uniform 1536-block packing (R10), hoisted bases.
// Axes measured to plateau this session: counted-vmcnt (R6 null), geometry
// (R7 null), 4-phase split (R8 regress), unroll (R12 null); swizzle/packing/
// nt real. If TLP is also null -> structural ceiling, declare next round.
// MODES: 1: a1=tanh(hx@W1^T+b1); 2: gates=act(a1@W2^T+b2), act=sigm(tanh)
// for i2/f2, tanh(sigm(tanh)) for z. Both GB=12 (3 nets x 4 ny per mtile).
// NOTE: never runtime-index acc[]/frag arrays (scratch spill lesson).
// ---------------------------------------------------------------------------
template <int MODE>
__global__ __launch_bounds__(256) void gemm_kernel(
    const __bf16* __restrict__ Ab,     // MODE1: hxb [M][512]; else a1 planes
    const __bf16* __restrict__ W,      // [3][512][512] bf16 (N,K) row-major
    const float* __restrict__ bias,    // [7][512] fp32
    __bf16* __restrict__ outb)         // MODE1: a1; MODE2: gates [3][M][512]
{
  // XCD-chunked bijective swizzle (grid.x = 1536, %8 == 0).
  const int bid = blockIdx.x;
  const int cpx = gridDim.x >> 3;                  // blocks per XCD chunk
  const int wg  = (bid & 7) * cpx + (bid >> 3);    // logical wg id
  const int mtile = wg / 12;                       // 12 wgs per mtile
  const int rem   = wg % 12;
  const int ny    = rem & 3;
  const int jj    = rem >> 2;                      // net index 0..2
  const int mbase = mtile * 128;
  const int nbase = ny * 128;
  constexpr size_t NH = (size_t)M * 512;

  const __bf16* Aj = (MODE == 1) ? Ab : Ab + (size_t)jj * NH;
  const __bf16* Wj = W + (size_t)jj * 262144;
  const int brow = 2 * jj + 1;                // bias row: i2=1, f2=3, z=5

  // 2 staging buffers x 8192 el (16KB each) = 32KB -> 5 blocks/CU.
  // Epilogue scratch reuses the full 16384 el ([128][128], kswz'd).
  __shared__ __align__(16) __bf16 smem[16384];

  const int tid  = threadIdx.x;
  const int wid  = tid >> 6;
  const int lane = tid & 63;
  const int wm   = (wid >> 1) * 64;
  const int wn   = (wid & 1) * 64;
  const int srow = wid * 16 + (lane >> 2);
  const int scol = ((lane & 3) ^ ((lane >> 3) & 3)) * 8;  // swizzled src chunk
  const int fr   = lane & 15;
  const int kc   = lane >> 4;
  const int sw   = (fr >> 1) & 3;
  const int rowq = kc * 4;

  // Loop-invariant bases (R12); per-step deltas fold to immediates.
  const __bf16* Asrc0 = Aj + (size_t)(mbase + srow) * K + scol;
  const __bf16* Asrc1 = Aj + (size_t)(mbase + 64 + srow) * K + scol;
  const __bf16* Bsrc0 = Wj + (size_t)(nbase + srow) * K + scol;
  const __bf16* Bsrc1 = Wj + (size_t)(nbase + 64 + srow) * K + scol;
  __bf16* const Adst0 = smem + (wid * 16) * BK;
  __bf16* const Adst1 = smem + (64 + wid * 16) * BK;
  __bf16* const Bdst0 = smem + 4096 + (wid * 16) * BK;
  __bf16* const Bdst1 = smem + 4096 + (64 + wid * 16) * BK;

  auto stage = [&](int p, int k0) {
    async_copy16(Asrc0 + k0, (void*)(Adst0 + p * 8192));
    async_copy16(Asrc1 + k0, (void*)(Adst1 + p * 8192));
    async_copy16(Bsrc0 + k0, (void*)(Bdst0 + p * 8192));
    async_copy16(Bsrc1 + k0, (void*)(Bdst1 + p * 8192));
  };

  f32x4 acc[4][4] = {};

  stage(0, 0);
#pragma unroll
  for (int t = 0; t < NT; ++t) {
    const int p = t & 1;
    __syncthreads();                      // publishes buffer p (R0-proven)
    if (t + 1 < NT) stage(p ^ 1, (t + 1) * BK);   // in flight during MFMA

    const __bf16* As = smem + p * 8192;
    const __bf16* Bs = As + 4096;
    bf16x8 af[4], bfr[4];
#pragma unroll
    for (int i = 0; i < 4; ++i) {
      af[i]  = *(const bf16x8*)&As[(wm + i * 16 + fr) * BK + ((kc ^ sw) * 8)];
      bfr[i] = *(const bf16x8*)&Bs[(wn + i * 16 + fr) * BK + ((kc ^ sw) * 8)];
    }
#pragma unroll
    for (int mi = 0; mi < 4; ++mi)
#pragma unroll
      for (int ni = 0; ni < 4; ++ni)
        acc[mi][ni] = __builtin_amdgcn_mfma_f32_16x16x32_bf16(
            af[mi], bfr[ni], acc[mi][ni], 0, 0, 0);
  }

  // Epilogue. C/D layout: col=fr, row=rowq+r.
  float bv[4];
  const float* bj = bias + (size_t)brow * 512 + nbase + wn;
#pragma unroll
  for (int ni = 0; ni < 4; ++ni) bv[ni] = bj[ni * 16 + fr];

  __syncthreads();  // all frag reads done; smem reusable as C scratch
#pragma unroll
  for (int mi = 0; mi < 4; ++mi)
#pragma unroll
    for (int ni = 0; ni < 4; ++ni)
#pragma unroll
      for (int r = 0; r < 4; ++r) {
        float v = acc[mi][ni][r] + bv[ni];
        float res;
        if constexpr (MODE == 1) res = ftanh(v);
        else res = (jj == 2) ? ftanh(fsigm(ftanh(v)))   // z, stored tanh'd
                             : fsigm(ftanh(v));         // i2 / f2
        const int row = wm + mi * 16 + rowq + r;
        const int col = wn + ni * 16 + fr;
        smem[row * 128 + (col ^ kswz(row))] = (__bf16)res;
      }
  __syncthreads();
#pragma unroll
  for (int it = 0; it < 8; ++it) {
    const int s = it * 256 + tid;   // 0..2047
    const int row = s >> 4, ch = s & 15;
    bf16x8 v = *(const bf16x8*)&smem[row * 128 + ((ch * 8) ^ kswz(row))];
    bf16x8* dst = (bf16x8*)&outb[(size_t)jj * NH + (size_t)(mbase + row) * 512 +
                                 (nbase + ch * 8)];
    if constexpr (MODE == 2)
      __builtin_nontemporal_store(v, dst);  // gates: stream-once, protect L3
    else
      *dst = v;                             // a1: KEEP cached (reused by g2)
  }
}

// cy2 = f2*cx2 + i2*z   gates = [i2 | f2 | z(tanh'd)] bf16 [3][M][512]
// (R0-proven streaming kernel; all traffic stream-once -> fully nt)
__global__ __launch_bounds__(256) void final_kernel(
    const __bf16* __restrict__ gates, const float* __restrict__ cx2,
    float* __restrict__ out)
{
  constexpr size_t NH = (size_t)M * 512;
  const size_t i = ((size_t)blockIdx.x * 256 + threadIdx.x) * 8;
  bf16x8 i2 = __builtin_nontemporal_load((const bf16x8*)&gates[i]);
  bf16x8 f2 = __builtin_nontemporal_load((const bf16x8*)&gates[NH + i]);
  bf16x8 zz = __builtin_nontemporal_load((const bf16x8*)&gates[2 * NH + i]);
  f32x4 c0 = __builtin_nontemporal_load((const f32x4*)&cx2[i]);
  f32x4 c1 = __builtin_nontemporal_load((const f32x4*)&cx2[i + 4]);
#pragma unroll
  for (int h = 0; h < 2; ++h) {
    f32x4 r;
#pragma unroll
    for (int q = 0; q < 4; ++q) {
      const int e = h * 4 + q;
      r[q] = (float)f2[e] * (h ? c1[q] : c0[q]) + (float)i2[e] * (float)zz[e];
    }
    __builtin_nontemporal_store(r, (f32x4*)&out[i + h * 4]);
  }
}

// One conversion dispatch: blocks [0,1536) pick rows 2y+1 of W1/W2
// ([7][512][512] fp32) -> Wb [6][512][512] bf16; blocks [1536,9728) convert
// hx [M][512] fp32 -> hxb bf16. fp32 sources are read-once -> nt loads;
// bf16 outputs are re-read by the GEMMs -> normal stores.
__global__ __launch_bounds__(256) void cvt_all(const float* __restrict__ hx,
                                               const float* __restrict__ W1,
                                               const float* __restrict__ W2,
                                               __bf16* __restrict__ hxb,
                                               __bf16* __restrict__ Wb) {
  const int b = blockIdx.x;
  if (b < 1536) {
    const int y = b >> 8;          // 0..5
    const int bb = b & 255;
    const float* src = (y < 3) ? W1 + (size_t)(2 * y + 1) * 262144
                               : W2 + (size_t)(2 * (y - 3) + 1) * 262144;
    __bf16* d = Wb + (size_t)y * 262144;
    const size_t i = ((size_t)bb * 256 + threadIdx.x) * 4;
    f32x4 v = __builtin_nontemporal_load((const f32x4*)&src[i]);
    *(bf16x4*)&d[i] = __builtin_convertvector(v, bf16x4);
  } else {
    const size_t i = ((size_t)(b - 1536) * 256 + threadIdx.x) * 4;
    f32x4 v = __builtin_nontemporal_load((const f32x4*)&hx[i]);
    *(bf16x4*)&hxb[i] = __builtin_convertvector(v, bf16x4);
  }
}

extern "C" void kernel_launch(void* const* d_in, const int* in_sizes, int n_in,
                              void* d_out, int out_size, void* d_ws, size_t ws_size,
                              hipStream_t stream) {
  const float* hx  = (const float*)d_in[0];
  // d_in[1] = cx1 (dead: cy1 is never returned)
  const float* cx2 = (const float*)d_in[2];
  const float* W1  = (const float*)d_in[3];
  const float* b1  = (const float*)d_in[4];
  const float* W2  = (const float*)d_in[5];
  const float* b2  = (const float*)d_in[6];
  float* out = (float*)d_out;

  // ws: Wb @0 (3MB, [6] planes: 0-2=W1, 3-5=W2) | hxb @3MB (16MB) |
  //     a1 @19922944 (48MB) | gates @70254592 (48MB: i2,f2,z) -> ~118MB
  char* ws = (char*)d_ws;
  __bf16* Wb    = (__bf16*)(ws);
  __bf16* hxb   = (__bf16*)(ws + 3145728);
  __bf16* a1    = (__bf16*)(ws + 19922944);
  __bf16* gates = (__bf16*)(ws + 70254592);
  __bf16* W2b   = Wb + 3 * 262144;

  cvt_all<<<9728, 256, 0, stream>>>(hx, W1, W2, hxb, Wb);

  // layer 1 (3 nets): 1536 wgs = 128 mtiles x 12
  gemm_kernel<1><<<1536, 256, 0, stream>>>(hxb, Wb, b1, a1);
  // layer 2 (3 nets incl z): 1536 wgs
  gemm_kernel<2><<<1536, 256, 0, stream>>>(a1, W2b, b2, gates);
  // combine (perfectly packed streaming, fully nt)
  final_kernel<<<4096, 256, 0, stream>>>(gates, cx2, out);
}

// Round 14
// 221.953 us; speedup vs baseline: 1.0394x; 1.0394x over previous
//
#include <hip/hip_runtime.h>
#include <hip/hip_bf16.h>

typedef __attribute__((ext_vector_type(8))) __bf16 bf16x8;
typedef __attribute__((ext_vector_type(4))) __bf16 bf16x4;
typedef __attribute__((ext_vector_type(4))) float f32x4;

constexpr int M = 16384;
constexpr int K = 512;
constexpr int BK = 32;
constexpr int NT = 16;       // K / BK

__device__ __forceinline__ void async_copy16(const void* gsrc, void* ldst) {
  __builtin_amdgcn_global_load_lds(
      (const __attribute__((address_space(1))) unsigned int*)(gsrc),
      (__attribute__((address_space(3))) unsigned int*)(ldst),
      16, 0, 0);
}

__device__ __forceinline__ float frcp(float x) { return __builtin_amdgcn_rcpf(x); }
__device__ __forceinline__ float ftanh(float x) {
  return 1.0f - 2.0f * frcp(1.0f + __expf(2.0f * x));
}
__device__ __forceinline__ float fsigm(float x) { return frcp(1.0f + __expf(-x)); }

// Epilogue scratch swizzle (R4-proven): row stride 128 els (256B, bank-
// aligned); per-row XOR on the 8-el chunk gives the 4 kc row-groups distinct
// shifts -> stores 2-way max (free), reads cover each row once.
__device__ __forceinline__ int kswz(int row) {
  return ((row & 3) << 3) ^ ((row & 12) << 2);
}

// ---------------------------------------------------------------------------
// R14 = R11 VERBATIM (session best, 218.9us) - close-out pin.
// Session ledger (what's real on this problem, LSTM cell M=16384 K=N=512):
//   REAL: XCD-chunked block swizzle (R9: FETCH 31->15MB on g1);
//         uniform 1536-block round packing (R10); nt hints on stream-once
//         traffic protecting a1's L3 residency (R11: g2 67->46us);
//         3-buffer lead-2 staging at 3 blocks/CU (R13 showed lead-1/5-blk
//         regresses; R8/m132 show fewer blocks regress too).
//   NULL/REGRESS: megafusion (R1/2: spill+no TLP), in-kernel fp32 A-cvt
//         (R4), counted-vmcnt alone (R6), 8x4 wave-tile (R7), 4-phase
//         m201-style split (R8), full unroll (R12), lead-1 TLP (R13).
// Structural constraint: GEMMs ~570TF = 2-phase-barrier latency plateau at
// K=512 (16 K-steps, drain exposed per step); the known escape (8-phase
// co-design) regresses at this shape (R8). Kernel time ~121us; ~98us fixed
// harness overhead. No unfalsified mechanism remains in this session.
// MODES: 1: a1=tanh(hx@W1^T+b1); 2: gates=act(a1@W2^T+b2), act=sigm(tanh)
// for i2/f2, tanh(sigm(tanh)) for z. Both GB=12 (3 nets x 4 ny per mtile).
// LDS: 3 staging buffers (48KB) -> 3 blocks/CU; scratch reuses [0..16383].
// NOTE: never runtime-index acc[]/frag arrays (scratch spill lesson).
// ---------------------------------------------------------------------------
template <int MODE>
__global__ __launch_bounds__(256) void gemm_kernel(
    const __bf16* __restrict__ Ab,     // MODE1: hxb [M][512]; else a1 planes
    const __bf16* __restrict__ W,      // [3][512][512] bf16 (N,K) row-major
    const float* __restrict__ bias,    // [7][512] fp32
    __bf16* __restrict__ outb)         // MODE1: a1; MODE2: gates [3][M][512]
{
  // XCD-chunked bijective swizzle (grid.x = 1536, %8 == 0).
  const int bid = blockIdx.x;
  const int cpx = gridDim.x >> 3;                  // blocks per XCD chunk
  const int wg  = (bid & 7) * cpx + (bid >> 3);    // logical wg id
  const int mtile = wg / 12;                       // 12 wgs per mtile
  const int rem   = wg % 12;
  const int ny    = rem & 3;
  const int jj    = rem >> 2;                      // net index 0..2
  const int mbase = mtile * 128;
  const int nbase = ny * 128;
  constexpr size_t NH = (size_t)M * 512;

  const __bf16* Aj = (MODE == 1) ? Ab : Ab + (size_t)jj * NH;
  const __bf16* Wj = W + (size_t)jj * 262144;
  const int brow = 2 * jj + 1;                // bias row: i2=1, f2=3, z=5

  // 3 staging buffers x 8192 el (16KB each) = 48KB; scratch reuses [0..16383]
  __shared__ __align__(16) __bf16 smem[24576];

  const int tid  = threadIdx.x;
  const int wid  = tid >> 6;
  const int lane = tid & 63;
  const int wm   = (wid >> 1) * 64;
  const int wn   = (wid & 1) * 64;
  const int srow = wid * 16 + (lane >> 2);
  const int scol = ((lane & 3) ^ ((lane >> 3) & 3)) * 8;  // swizzled src chunk
  const int fr   = lane & 15;
  const int kc   = lane >> 4;
  const int sw   = (fr >> 1) & 3;
  const int rowq = kc * 4;

  auto stage = [&](int p, int k0) {
    __bf16* As = smem + p * 8192;
    __bf16* Bs = As + 4096;
#pragma unroll
    for (int r = 0; r < 2; ++r) {
      async_copy16(Aj + (size_t)(mbase + r * 64 + srow) * K + (k0 + scol),
                   (void*)&As[(r * 64 + wid * 16) * BK]);
      async_copy16(Wj + (size_t)(nbase + r * 64 + srow) * K + (k0 + scol),
                   (void*)&Bs[(r * 64 + wid * 16) * BK]);
    }
  };

  f32x4 acc[4][4] = {};

  stage(0, 0);
  stage(1, BK);
  int pr = 0, ps = 2;
  for (int t = 0; t < NT; ++t) {
    // ONE waitcnt: retire this wave's ds_reads (lgkmcnt 0) AND everything
    // but the newest stage (vmcnt 4) BEFORE the barrier. Tile t+2's copies
    // stay in flight across it (never drain to 0 mid-loop).
    if (t < NT - 2) asm volatile("s_waitcnt vmcnt(4) lgkmcnt(0)" ::: "memory");
    else            asm volatile("s_waitcnt vmcnt(0) lgkmcnt(0)" ::: "memory");
    __builtin_amdgcn_s_barrier();
    __builtin_amdgcn_sched_barrier(0);   // rule #18: pin code below the bar
    if (t < NT - 2) stage(ps, (t + 2) * BK);

    const __bf16* As = smem + pr * 8192;
    const __bf16* Bs = As + 4096;
    bf16x8 af[4], bfr[4];
#pragma unroll
    for (int i = 0; i < 4; ++i) {
      af[i]  = *(const bf16x8*)&As[(wm + i * 16 + fr) * BK + ((kc ^ sw) * 8)];
      bfr[i] = *(const bf16x8*)&Bs[(wn + i * 16 + fr) * BK + ((kc ^ sw) * 8)];
    }
#pragma unroll
    for (int mi = 0; mi < 4; ++mi)
#pragma unroll
      for (int ni = 0; ni < 4; ++ni)
        acc[mi][ni] = __builtin_amdgcn_mfma_f32_16x16x32_bf16(
            af[mi], bfr[ni], acc[mi][ni], 0, 0, 0);

    pr = (pr == 2) ? 0 : pr + 1;
    ps = (ps == 2) ? 0 : ps + 1;
  }

  // Epilogue. C/D layout: col=fr, row=rowq+r.
  float bv[4];
  const float* bj = bias + (size_t)brow * 512 + nbase + wn;
#pragma unroll
  for (int ni = 0; ni < 4; ++ni) bv[ni] = bj[ni * 16 + fr];

  __syncthreads();  // full drain once; smem reusable as C scratch
#pragma unroll
  for (int mi = 0; mi < 4; ++mi)
#pragma unroll
    for (int ni = 0; ni < 4; ++ni)
#pragma unroll
      for (int r = 0; r < 4; ++r) {
        float v = acc[mi][ni][r] + bv[ni];
        float res;
        if constexpr (MODE == 1) res = ftanh(v);
        else res = (jj == 2) ? ftanh(fsigm(ftanh(v)))   // z, stored tanh'd
                             : fsigm(ftanh(v));         // i2 / f2
        const int row = wm + mi * 16 + rowq + r;
        const int col = wn + ni * 16 + fr;
        smem[row * 128 + (col ^ kswz(row))] = (__bf16)res;
      }
  __syncthreads();
#pragma unroll
  for (int it = 0; it < 8; ++it) {
    const int s = it * 256 + tid;   // 0..2047
    const int row = s >> 4, ch = s & 15;
    bf16x8 v = *(const bf16x8*)&smem[row * 128 + ((ch * 8) ^ kswz(row))];
    bf16x8* dst = (bf16x8*)&outb[(size_t)jj * NH + (size_t)(mbase + row) * 512 +
                                 (nbase + ch * 8)];
    if constexpr (MODE == 2)
      __builtin_nontemporal_store(v, dst);  // gates: stream-once, protect L3
    else
      *dst = v;                             // a1: KEEP cached (reused by g2)
  }
}

// cy2 = f2*cx2 + i2*z   gates = [i2 | f2 | z(tanh'd)] bf16 [3][M][512]
// (R0-proven streaming kernel; all traffic stream-once -> fully nt)
__global__ __launch_bounds__(256) void final_kernel(
    const __bf16* __restrict__ gates, const float* __restrict__ cx2,
    float* __restrict__ out)
{
  constexpr size_t NH = (size_t)M * 512;
  const size_t i = ((size_t)blockIdx.x * 256 + threadIdx.x) * 8;
  bf16x8 i2 = __builtin_nontemporal_load((const bf16x8*)&gates[i]);
  bf16x8 f2 = __builtin_nontemporal_load((const bf16x8*)&gates[NH + i]);
  bf16x8 zz = __builtin_nontemporal_load((const bf16x8*)&gates[2 * NH + i]);
  f32x4 c0 = __builtin_nontemporal_load((const f32x4*)&cx2[i]);
  f32x4 c1 = __builtin_nontemporal_load((const f32x4*)&cx2[i + 4]);
#pragma unroll
  for (int h = 0; h < 2; ++h) {
    f32x4 r;
#pragma unroll
    for (int q = 0; q < 4; ++q) {
      const int e = h * 4 + q;
      r[q] = (float)f2[e] * (h ? c1[q] : c0[q]) + (float)i2[e] * (float)zz[e];
    }
    __builtin_nontemporal_store(r, (f32x4*)&out[i + h * 4]);
  }
}

// One conversion dispatch: blocks [0,1536) pick rows 2y+1 of W1/W2
// ([7][512][512] fp32) -> Wb [6][512][512] bf16; blocks [1536,9728) convert
// hx [M][512] fp32 -> hxb bf16. fp32 sources are read-once -> nt loads;
// bf16 outputs are re-read by the GEMMs -> normal stores.
__global__ __launch_bounds__(256) void cvt_all(const float* __restrict__ hx,
                                               const float* __restrict__ W1,
                                               const float* __restrict__ W2,
                                               __bf16* __restrict__ hxb,
                                               __bf16* __restrict__ Wb) {
  const int b = blockIdx.x;
  if (b < 1536) {
    const int y = b >> 8;          // 0..5
    const int bb = b & 255;
    const float* src = (y < 3) ? W1 + (size_t)(2 * y + 1) * 262144
                               : W2 + (size_t)(2 * (y - 3) + 1) * 262144;
    __bf16* d = Wb + (size_t)y * 262144;
    const size_t i = ((size_t)bb * 256 + threadIdx.x) * 4;
    f32x4 v = __builtin_nontemporal_load((const f32x4*)&src[i]);
    *(bf16x4*)&d[i] = __builtin_convertvector(v, bf16x4);
  } else {
    const size_t i = ((size_t)(b - 1536) * 256 + threadIdx.x) * 4;
    f32x4 v = __builtin_nontemporal_load((const f32x4*)&hx[i]);
    *(bf16x4*)&hxb[i] = __builtin_convertvector(v, bf16x4);
  }
}

extern "C" void kernel_launch(void* const* d_in, const int* in_sizes, int n_in,
                              void* d_out, int out_size, void* d_ws, size_t ws_size,
                              hipStream_t stream) {
  const float* hx  = (const float*)d_in[0];
  // d_in[1] = cx1 (dead: cy1 is never returned)
  const float* cx2 = (const float*)d_in[2];
  const float* W1  = (const float*)d_in[3];
  const float* b1  = (const float*)d_in[4];
  const float* W2  = (const float*)d_in[5];
  const float* b2  = (const float*)d_in[6];
  float* out = (float*)d_out;

  // ws: Wb @0 (3MB, [6] planes: 0-2=W1, 3-5=W2) | hxb @3MB (16MB) |
  //     a1 @19922944 (48MB) | gates @70254592 (48MB: i2,f2,z) -> ~118MB
  char* ws = (char*)d_ws;
  __bf16* Wb    = (__bf16*)(ws);
  __bf16* hxb   = (__bf16*)(ws + 3145728);
  __bf16* a1    = (__bf16*)(ws + 19922944);
  __bf16* gates = (__bf16*)(ws + 70254592);
  __bf16* W2b   = Wb + 3 * 262144;

  cvt_all<<<9728, 256, 0, stream>>>(hx, W1, W2, hxb, Wb);

  // layer 1 (3 nets): 1536 wgs = 128 mtiles x 12 -> exactly 2 full rounds
  gemm_kernel<1><<<1536, 256, 0, stream>>>(hxb, Wb, b1, a1);
  // layer 2 (3 nets incl z): 1536 wgs -> exactly 2 full rounds
  gemm_kernel<2><<<1536, 256, 0, stream>>>(a1, W2b, b2, gates);
  // combine (perfectly packed streaming, fully nt)
  final_kernel<<<4096, 256, 0, stream>>>(gates, cx2, out);
}